// Round 6
// baseline (4212.260 us; speedup 1.0000x reference)
//
#include <hip/hip_runtime.h>
#include <hip/hip_bf16.h>
#include <math.h>

#define N_NODES 8192
#define D_DLG   64
#define L_SEQ   128
#define H_DIM   512
#define N_HEADS 8
#define DHEAD   64
#define FF_DIM  2048
#define E_EDGES 32768

typedef __hip_bfloat16 bf16;
typedef __attribute__((ext_vector_type(8))) short short8;
typedef __attribute__((ext_vector_type(4))) float f32x4;

// ---------------- load/store helpers (bf16 <-> f32) -------------------------
__device__ __forceinline__ float bconv(unsigned short u) {
    return __uint_as_float((unsigned)u << 16);
}
__device__ __forceinline__ unsigned short fconv(float f) {
    bf16 h = __float2bfloat16(f);
    return *(unsigned short*)&h;
}
__device__ __forceinline__ float4 ld4(const float* p) { return *(const float4*)p; }
__device__ __forceinline__ float4 ld4(const bf16* p) {
    ushort4 u = *(const ushort4*)p;
    float4 v;
    v.x = bconv(u.x); v.y = bconv(u.y); v.z = bconv(u.z); v.w = bconv(u.w);
    return v;
}
__device__ __forceinline__ float ld1(const float* p) { return *p; }
__device__ __forceinline__ float ld1(const bf16* p) { return bconv(*(const unsigned short*)p); }
__device__ __forceinline__ void st1(float* p, float v) { *p = v; }
__device__ __forceinline__ void st1(bf16* p, float v) { *p = __float2bfloat16(v); }

__device__ __forceinline__ void gld_lds16(const bf16* g, bf16* l) {
    __builtin_amdgcn_global_load_lds(
        (const __attribute__((address_space(1))) void*)g,
        (__attribute__((address_space(3))) void*)l, 16, 0, 0);
}

// ---------------------------------------------------------------------------
// Weight pre-pass: f32 [z][K][N] -> bf16 [z][N][K] (transpose + convert).
// ---------------------------------------------------------------------------
__global__ __launch_bounds__(256) void transpose_k(const float* __restrict__ in,
                                                   bf16* __restrict__ out, int K, int N)
{
    __shared__ float tile[32][33];
    const long zoff = (long)blockIdx.z * K * N;
    const int n0 = blockIdx.x * 32, k0 = blockIdx.y * 32;
    const int tx = threadIdx.x, ty = threadIdx.y;
#pragma unroll
    for (int i = 0; i < 4; ++i)
        tile[ty + i * 8][tx] = in[zoff + (long)(k0 + ty + i * 8) * N + n0 + tx];
    __syncthreads();
#pragma unroll
    for (int i = 0; i < 4; ++i)
        st1(out + zoff + (long)(n0 + ty + i * 8) * K + k0 + tx, tile[tx][ty + i * 8]);
}

// ---------------------------------------------------------------------------
// MFMA GEMM: C = act(A @ Bt^T + bias). A bf16 [M][K] (lda), Bt bf16 [N][K]
// (ldb), C row-major (ldc). 128x128 tile, BK=32, 4 waves, 4x4 mfma/wave.
// ---------------------------------------------------------------------------
template <typename TC>
__global__ __launch_bounds__(256) void mgemm_k(
    const bf16* __restrict__ A, const bf16* __restrict__ Bt,
    const float* __restrict__ bias, TC* __restrict__ C,
    int M, int K, int Ncols, int lda, int ldb, int ldc,
    long sA, long sB, long sC, int act)
{
    A  += (long)blockIdx.z * sA;
    Bt += (long)blockIdx.z * sB;
    C  += (long)blockIdx.z * sC;

    __shared__ bf16 As[128 * 32];
    __shared__ bf16 Bs[128 * 32];

    const int tid  = threadIdx.x;
    const int lane = tid & 63;
    const int wave = tid >> 6;
    const int wr   = wave >> 1;
    const int wc   = wave & 1;
    const int rowTile = blockIdx.y * 128;
    const int colTile = blockIdx.x * 128;

    const int c0 = wave * 2, c1 = wave * 2 + 1;
    const int b0 = c0 * 1024 + lane * 16;
    const int b1 = c1 * 1024 + lane * 16;
    const int ar0 = b0 >> 6, ak0 = (b0 & 63) >> 1;
    const int ar1 = b1 >> 6, ak1 = (b1 & 63) >> 1;

    const int frow = lane & 15;
    const int kgrp = lane >> 4;

    f32x4 acc[4][4];
#pragma unroll
    for (int i = 0; i < 4; ++i)
#pragma unroll
        for (int j = 0; j < 4; ++j) acc[i][j] = (f32x4){0.f, 0.f, 0.f, 0.f};

    for (int k0 = 0; k0 < K; k0 += 32) {
        gld_lds16(A  + (long)(rowTile + ar0) * lda + k0 + ak0, As + c0 * 512);
        gld_lds16(A  + (long)(rowTile + ar1) * lda + k0 + ak1, As + c1 * 512);
        gld_lds16(Bt + (long)(colTile + ar0) * ldb + k0 + ak0, Bs + c0 * 512);
        gld_lds16(Bt + (long)(colTile + ar1) * ldb + k0 + ak1, Bs + c1 * 512);
        __syncthreads();

        short8 av[4], bv[4];
#pragma unroll
        for (int mi = 0; mi < 4; ++mi)
            av[mi] = *(const short8*)(As + (wr * 64 + mi * 16 + frow) * 32 + kgrp * 8);
#pragma unroll
        for (int ni = 0; ni < 4; ++ni)
            bv[ni] = *(const short8*)(Bs + (wc * 64 + ni * 16 + frow) * 32 + kgrp * 8);
#pragma unroll
        for (int mi = 0; mi < 4; ++mi)
#pragma unroll
            for (int ni = 0; ni < 4; ++ni)
                acc[mi][ni] = __builtin_amdgcn_mfma_f32_16x16x32_bf16(
                    av[mi], bv[ni], acc[mi][ni], 0, 0, 0);
        __syncthreads();
    }

#pragma unroll
    for (int ni = 0; ni < 4; ++ni) {
        int col = colTile + wc * 64 + ni * 16 + frow;
        if (col < Ncols) {
            float bb = bias ? bias[col] : 0.f;
#pragma unroll
            for (int mi = 0; mi < 4; ++mi) {
                long rbase = rowTile + wr * 64 + mi * 16 + kgrp * 4;
#pragma unroll
                for (int r = 0; r < 4; ++r) {
                    float v = acc[mi][ni][r] + bb;
                    if (act == 1) v = fmaxf(v, 0.f);
                    st1(C + (rbase + r) * (long)ldc + col, v);
                }
            }
        }
    }
}

// ---------------------------------------------------------------------------
// Classifier head: out[N,7] = A[N,768] @ W[768,7] + bias. Wave per row.
// ---------------------------------------------------------------------------
__global__ __launch_bounds__(256) void head7_k(
    const bf16* __restrict__ A, const float* __restrict__ W,
    const float* __restrict__ bias, float* __restrict__ out)
{
    const int wave = threadIdx.x >> 6, lane = threadIdx.x & 63;
    const long row = blockIdx.x * 4 + wave;
    const bf16* a = A + row * 768;
    float acc[7];
#pragma unroll
    for (int j = 0; j < 7; ++j) acc[j] = 0.f;
#pragma unroll
    for (int i = 0; i < 12; ++i) {
        int k = lane + i * 64;
        float av = ld1(a + k);
        const float* w = W + k * 7;
#pragma unroll
        for (int j = 0; j < 7; ++j) acc[j] = fmaf(av, w[j], acc[j]);
    }
#pragma unroll
    for (int j = 0; j < 7; ++j)
#pragma unroll
        for (int o = 32; o > 0; o >>= 1) acc[j] += __shfl_down(acc[j], o, 64);
    if (lane == 0) {
#pragma unroll
        for (int j = 0; j < 7; ++j) out[row * 7 + j] = acc[j] + bias[j];
    }
}

// ---------------------------------------------------------------------------
__global__ void xcat_k(const float* __restrict__ x, const float* __restrict__ spk_emb,
                       const int* __restrict__ sidx, bf16* __restrict__ out, int n_total)
{
    int i = blockIdx.x * 256 + threadIdx.x;
    if (i >= n_total) return;
    int n = i / 576;
    int c = i - n * 576;
    st1(out + i, (c < 512) ? x[(long)n * 512 + c]
                           : spk_emb[(long)sidx[n] * 64 + (c - 512)]);
}

// ---------------------------------------------------------------------------
// Per-(dialogue, head) attention. K/V staged in LDS as bf16 (32 KB/block ->
// 4 blocks/CU = 8 waves/CU vs 2 with fp32). fp32 accumulate.
// ---------------------------------------------------------------------------
__global__ __launch_bounds__(128) void attn_k(const bf16* __restrict__ qkv,
                                              bf16* __restrict__ o)
{
    const int d = blockIdx.x;
    const int h = blockIdx.y;
    __shared__ bf16 Ks[L_SEQ * DHEAD];
    __shared__ bf16 Vs[L_SEQ * DHEAD];
    const int tid = threadIdx.x;
    const long base = (long)d * L_SEQ;

    const int rowOff = tid >> 4;
    const int q4 = (tid & 15) * 4;
    const unsigned short* qs = (const unsigned short*)qkv;
    for (int r0 = 0; r0 < L_SEQ; r0 += 8) {
        int row = r0 + rowOff;
        long g = (base + row) * 1536;
        *(ushort4*)((unsigned short*)Ks + row * DHEAD + q4) = *(const ushort4*)(qs + g + 512  + h * 64 + q4);
        *(ushort4*)((unsigned short*)Vs + row * DHEAD + q4) = *(const ushort4*)(qs + g + 1024 + h * 64 + q4);
    }
    __syncthreads();

    float4 qr[16];
    {
        long gq = (base + tid) * 1536 + h * 64;
#pragma unroll
        for (int i = 0; i < 16; ++i) qr[i] = ld4(qkv + gq + i * 4);
    }
    float m = -1e30f, ss = 0.f;
    float4 oa[16];
#pragma unroll
    for (int i = 0; i < 16; ++i) { oa[i].x = 0.f; oa[i].y = 0.f; oa[i].z = 0.f; oa[i].w = 0.f; }

    for (int k = 0; k < L_SEQ; ++k) {
        const bf16* Krow = Ks + k * DHEAD;
        float dot = 0.f;
#pragma unroll
        for (int i = 0; i < 16; ++i) {
            float4 kv = ld4(Krow + i * 4);
            dot = fmaf(qr[i].x, kv.x, dot);
            dot = fmaf(qr[i].y, kv.y, dot);
            dot = fmaf(qr[i].z, kv.z, dot);
            dot = fmaf(qr[i].w, kv.w, dot);
        }
        dot *= 0.125f;
        float mn = fmaxf(m, dot);
        float sc = __expf(m - mn);
        float p  = __expf(dot - mn);
        ss = ss * sc + p;
        m = mn;
        const bf16* Vrow = Vs + k * DHEAD;
#pragma unroll
        for (int i = 0; i < 16; ++i) {
            float4 vv = ld4(Vrow + i * 4);
            oa[i].x = oa[i].x * sc + p * vv.x;
            oa[i].y = oa[i].y * sc + p * vv.y;
            oa[i].z = oa[i].z * sc + p * vv.z;
            oa[i].w = oa[i].w * sc + p * vv.w;
        }
    }
    float inv = 1.f / ss;
    long go = (base + tid) * H_DIM + h * 64;
#pragma unroll
    for (int i = 0; i < 16; ++i) {
        float4 v; v.x = oa[i].x * inv; v.y = oa[i].y * inv; v.z = oa[i].z * inv; v.w = oa[i].w * inv;
        ushort4 u;
        u.x = fconv(v.x); u.y = fconv(v.y); u.z = fconv(v.z); u.w = fconv(v.w);
        *(ushort4*)((unsigned short*)o + go + i * 4) = u;
    }
}

// ---------------------------------------------------------------------------
__global__ __launch_bounds__(256) void add_ln_k(bf16* __restrict__ h, const bf16* __restrict__ r,
                                                const float* __restrict__ g, const float* __restrict__ b)
{
    const int row = blockIdx.x;
    const int tid = threadIdx.x;
    const long base = (long)row * 512;
    float x0 = ld1(h + base + tid) + ld1(r + base + tid);
    float x1 = ld1(h + base + tid + 256) + ld1(r + base + tid + 256);
    float s = x0 + x1;
    float q = x0 * x0 + x1 * x1;
#pragma unroll
    for (int o = 32; o > 0; o >>= 1) { s += __shfl_down(s, o, 64); q += __shfl_down(q, o, 64); }
    __shared__ float ls[4], lq[4];
    if ((tid & 63) == 0) { ls[tid >> 6] = s; lq[tid >> 6] = q; }
    __syncthreads();
    float S = ls[0] + ls[1] + ls[2] + ls[3];
    float Q = lq[0] + lq[1] + lq[2] + lq[3];
    float mu = S * (1.f / 512.f);
    float var = Q * (1.f / 512.f) - mu * mu;
    float inv = rsqrtf(fmaxf(var, 0.f) + 1e-5f);
    st1(h + base + tid,       (x0 - mu) * inv * g[tid] + b[tid]);
    st1(h + base + tid + 256, (x1 - mu) * inv * g[tid + 256] + b[tid + 256]);
}

__global__ __launch_bounds__(256) void skip_ln_relu_k(
    const float* __restrict__ outp, const bf16* __restrict__ curp, bf16* __restrict__ dst,
    const float* __restrict__ gskip, const float* __restrict__ g, const float* __restrict__ b)
{
    const int row = blockIdx.x;
    const int tid = threadIdx.x;
    const float beta = 1.f / (1.f + __expf(-gskip[0]));
    const long base = (long)row * 512;
    float x0 = beta * outp[base + tid]       + (1.f - beta) * ld1(curp + base + tid);
    float x1 = beta * outp[base + tid + 256] + (1.f - beta) * ld1(curp + base + tid + 256);
    float s = x0 + x1;
    float q = x0 * x0 + x1 * x1;
#pragma unroll
    for (int o = 32; o > 0; o >>= 1) { s += __shfl_down(s, o, 64); q += __shfl_down(q, o, 64); }
    __shared__ float ls[4], lq[4];
    if ((tid & 63) == 0) { ls[tid >> 6] = s; lq[tid >> 6] = q; }
    __syncthreads();
    float S = ls[0] + ls[1] + ls[2] + ls[3];
    float Q = lq[0] + lq[1] + lq[2] + lq[3];
    float mu = S * (1.f / 512.f);
    float var = Q * (1.f / 512.f) - mu * mu;
    float inv = rsqrtf(fmaxf(var, 0.f) + 1e-5f);
    float y0 = (x0 - mu) * inv * g[tid] + b[tid];
    float y1 = (x1 - mu) * inv * g[tid + 256] + b[tid + 256];
    st1(dst + base + tid,       fmaxf(y0, 0.f));
    st1(dst + base + tid + 256, fmaxf(y1, 0.f));
}

// ---------------------------------------------------------------------------
__device__ __forceinline__ unsigned enc_f(float f) {
    unsigned u = __float_as_uint(f);
    return (u & 0x80000000u) ? ~u : (u | 0x80000000u);
}
__device__ __forceinline__ float dec_f(unsigned u) {
    return (u & 0x80000000u) ? __uint_as_float(u & 0x7fffffffu) : __uint_as_float(~u);
}

__global__ void edge_logit_k(float* __restrict__ lg, const bf16* __restrict__ qq,
                             const bf16* __restrict__ ktmp, const int* __restrict__ src,
                             const int* __restrict__ dst, const float* __restrict__ prel, int E)
{
    int tid = blockIdx.x * 256 + threadIdx.x;
    int e = tid >> 3;
    int h = tid & 7;
    if (e >= E) return;
    const bf16* qp = qq   + (long)dst[e] * 512 + h * 64;
    const bf16* kp = ktmp + (long)src[e] * 512 + h * 64;
    float acc = 0.f;
#pragma unroll
    for (int i = 0; i < 64; i += 4) {
        float4 a = ld4(qp + i);
        float4 c = ld4(kp + i);
        acc = fmaf(a.x, c.x, acc); acc = fmaf(a.y, c.y, acc);
        acc = fmaf(a.z, c.z, acc); acc = fmaf(a.w, c.w, acc);
    }
    lg[(long)e * 8 + h] = acc * prel[h] * 0.125f;
}

__global__ void init_stats_k(unsigned* __restrict__ m, float* __restrict__ s, int n)
{
    int i = blockIdx.x * 256 + threadIdx.x;
    if (i < n) { m[i] = 0x007FFFFFu; s[i] = 0.f; }
}

// grid.y = 2 -> relation r0 / r1
__global__ void edge_max2_k(const float* __restrict__ lgbuf, const int* __restrict__ ei,
                            unsigned* __restrict__ m, int r0, int r1)
{
    int r = blockIdx.y ? r1 : r0;
    const float* lg = lgbuf + (long)r * E_EDGES * 8;
    const int* dst = ei + ((long)r * 2 + 1) * E_EDGES;
    int tid = blockIdx.x * 256 + threadIdx.x;
    int e = tid >> 3;
    int h = tid & 7;
    if (e >= E_EDGES) return;
    atomicMax(&m[(long)dst[e] * 8 + h], enc_f(lg[(long)e * 8 + h]));
}

__global__ void edge_exp2_k(float* __restrict__ lgbuf, const int* __restrict__ ei,
                            const unsigned* __restrict__ m, float* __restrict__ s,
                            int r0, int r1)
{
    int r = blockIdx.y ? r1 : r0;
    float* lg = lgbuf + (long)r * E_EDGES * 8;
    const int* dst = ei + ((long)r * 2 + 1) * E_EDGES;
    int tid = blockIdx.x * 256 + threadIdx.x;
    int e = tid >> 3;
    int h = tid & 7;
    if (e >= E_EDGES) return;
    long si = (long)dst[e] * 8 + h;
    float mv = dec_f(m[si]);
    float ev = __expf(lg[(long)e * 8 + h] - mv);
    lg[(long)e * 8 + h] = ev;
    atomicAdd(&s[si], ev);
}

// lg := alpha = lg / (s[dst] + eps)   (in place)
__global__ void edge_alpha2_k(float* __restrict__ lgbuf, const int* __restrict__ ei,
                              const float* __restrict__ s, int r0, int r1)
{
    int r = blockIdx.y ? r1 : r0;
    float* lg = lgbuf + (long)r * E_EDGES * 8;
    const int* dst = ei + ((long)r * 2 + 1) * E_EDGES;
    int tid = blockIdx.x * 256 + threadIdx.x;
    int e = tid >> 3;
    int h = tid & 7;
    if (e >= E_EDGES) return;
    lg[(long)e * 8 + h] = lg[(long)e * 8 + h] / (s[(long)dst[e] * 8 + h] + 1e-9f);
}

// grid.y = 2; vtmp = vt0 / vt1; alpha precomputed in lgbuf
__global__ void edge_scatter2_k(const float* __restrict__ lgbuf, const int* __restrict__ ei,
                                const bf16* __restrict__ vt0, const bf16* __restrict__ vt1,
                                float* __restrict__ agg, int r0, int r1)
{
    int gi = blockIdx.y;
    int r = gi ? r1 : r0;
    const float* lg = lgbuf + (long)r * E_EDGES * 8;
    const int* src = ei + ((long)r * 2 + 0) * E_EDGES;
    const int* dst = ei + ((long)r * 2 + 1) * E_EDGES;
    const bf16* vtmp = gi ? vt1 : vt0;
    int tid = blockIdx.x * 256 + threadIdx.x;
    int e = tid >> 9;
    int c = tid & 511;
    int h = c >> 6;
    if (e >= E_EDGES) return;
    int de = dst[e];
    float a = lg[(long)e * 8 + h];
    atomicAdd(&agg[(long)de * 512 + c], a * ld1(vtmp + (long)src[e] * 512 + c));
}

__global__ void zero_k(float* __restrict__ p, long n)
{
    long i = (long)blockIdx.x * 256 + threadIdx.x;
    if (i < n) p[i] = 0.f;
}

__global__ void gelu_k(const float* __restrict__ x, bf16* __restrict__ y, long n)
{
    long i = (long)blockIdx.x * 256 + threadIdx.x;
    if (i < n) {
        float v = x[i];
        float t = tanhf(0.79788456080286535588f * (v + 0.044715f * v * v * v));
        st1(y + i, 0.5f * v * (1.f + t));
    }
}

__global__ void concat3_k(const bf16* __restrict__ a, const bf16* __restrict__ b,
                          const bf16* __restrict__ c, bf16* __restrict__ out, int n_total)
{
    int i = blockIdx.x * 256 + threadIdx.x;
    if (i >= n_total) return;
    int n = i / 1536;
    int cc = i - n * 1536;
    const bf16* sp = (cc < 512) ? a : (cc < 1024 ? b : c);
    out[i] = sp[(long)n * 512 + (cc & 511)];
}

// ---------------------------------------------------------------------------
static inline void convT(hipStream_t st, const float* in, bf16* out, int K, int N, int z)
{
    dim3 g(N / 32, K / 32, z), b(32, 8);
    transpose_k<<<g, b, 0, st>>>(in, out, K, N);
}
static inline void mgemm(hipStream_t st, const bf16* A, const bf16* Bt, const float* bias,
                         bf16* C, int M, int K, int Ncols, int lda, int ldb, int ldc,
                         long sA, long sB, long sC, int z, int act)
{
    dim3 g((Ncols + 127) / 128, M / 128, z);
    mgemm_k<bf16><<<g, 256, 0, st>>>(A, Bt, bias, C, M, K, Ncols, lda, ldb, ldc, sA, sB, sC, act);
}
static inline void mgemm_f(hipStream_t st, const bf16* A, const bf16* Bt, const float* bias,
                           float* C, int M, int K, int Ncols, int lda, int ldb, int ldc, int act)
{
    dim3 g((Ncols + 127) / 128, M / 128, 1);
    mgemm_k<float><<<g, 256, 0, st>>>(A, Bt, bias, C, M, K, Ncols, lda, ldb, ldc, 0, 0, 0, act);
}

extern "C" void kernel_launch(void* const* d_in, const int* in_sizes, int n_in,
                              void* d_out, int out_size, void* d_ws, size_t ws_size,
                              hipStream_t stream)
{
    const float* x_audio = (const float*)d_in[0];
    const float* x_text  = (const float*)d_in[1];
    const float* x_video = (const float*)d_in[2];
    const float* spk_emb = (const float*)d_in[3];
    const float* proj_w  = (const float*)d_in[4];
    const float* proj_b  = (const float*)d_in[5];
    const float* t_qkv_w = (const float*)d_in[6];
    const float* t_qkv_b = (const float*)d_in[7];
    const float* t_out_w = (const float*)d_in[8];
    const float* t_out_b = (const float*)d_in[9];
    const float* t_ff1_w = (const float*)d_in[10];
    const float* t_ff1_b = (const float*)d_in[11];
    const float* t_ff2_w = (const float*)d_in[12];
    const float* t_ff2_b = (const float*)d_in[13];
    const float* t_ln1_g = (const float*)d_in[14];
    const float* t_ln1_b = (const float*)d_in[15];
    const float* t_ln2_g = (const float*)d_in[16];
    const float* t_ln2_b = (const float*)d_in[17];
    const float* g_k_w   = (const float*)d_in[18];
    const float* g_k_b   = (const float*)d_in[19];
    const float* g_q_w   = (const float*)d_in[20];
    const float* g_q_b   = (const float*)d_in[21];
    const float* g_v_w   = (const float*)d_in[22];
    const float* g_v_b   = (const float*)d_in[23];
    const float* g_a_w   = (const float*)d_in[24];
    const float* g_a_b   = (const float*)d_in[25];
    const float* g_skip  = (const float*)d_in[26];
    const float* g_arel  = (const float*)d_in[27];
    const float* g_mrel  = (const float*)d_in[28];
    const float* g_prel  = (const float*)d_in[29];
    const float* g_ln_g  = (const float*)d_in[30];
    const float* g_ln_b  = (const float*)d_in[31];
    const float* c1_w    = (const float*)d_in[32];
    const float* c1_b    = (const float*)d_in[33];
    const float* c2_w    = (const float*)d_in[34];
    const float* c2_b    = (const float*)d_in[35];
    const int* speaker_idx = (const int*)d_in[36];
    const int* edge_index  = (const int*)d_in[38];

    const int N = N_NODES;
    const long NH = (long)N_NODES * H_DIM;

    // ---- bf16-transposed weight region (~56 MB) ----------------------------
    bf16* Wbf = (bf16*)d_ws;
    long off = 0;
    bf16* projT = Wbf + off; off += 3L * 512 * 576;
    bf16* qkvT  = Wbf + off; off += 6L * 1536 * 512;
    bf16* outT  = Wbf + off; off += 6L * 512 * 512;
    bf16* ff1T  = Wbf + off; off += 6L * 2048 * 512;
    bf16* ff2T  = Wbf + off; off += 6L * 512 * 2048;
    bf16* gkT   = Wbf + off; off += 6L * 512 * 512;
    bf16* gqT   = Wbf + off; off += 6L * 512 * 512;
    bf16* gvT   = Wbf + off; off += 6L * 512 * 512;
    bf16* gaT   = Wbf + off; off += 6L * 512 * 512;
    bf16* arelT = Wbf + off; off += 96L * 64 * 64;
    bf16* mrelT = Wbf + off; off += 96L * 64 * 64;
    bf16* c1T   = Wbf + off; off += 768L * 1536;
    off += 4096;  // slack for N=64 tile over-reads

    // ---- activation workspace (~126 MB; total ~183 MB) ---------------------
    bf16* cur0  = Wbf + off;
    bf16* Kbuf  = cur0 + 3 * NH;
    bf16* QVbuf = Kbuf + 3 * NH;
    bf16* S     = QVbuf + 3 * NH;          // N*2048 scratch
    bf16* aux   = S + (long)N * 2048;      // 2*NH (aux2 = aux + NH)
    bf16* aux2  = aux + NH;

    bf16* xin   = S;
    bf16* qkvb  = S;
    bf16* attno = S + (long)N * 1536;
    bf16* outp  = S;
    bf16* ffb   = S;
    float* agg   = (float*)S;
    float* lgbuf = agg + NH;
    unsigned* mbuf = (unsigned*)(lgbuf + 6L * E_EDGES * 8);
    float* sbuf  = (float*)(mbuf + (long)N * 8);
    bf16* aout   = (bf16*)(sbuf + (long)N * 8);

    static const int META_S[6] = {0, 1, 0, 2, 1, 2};
    static const int META_D[6] = {1, 0, 2, 0, 2, 1};
    static const int GROUPS[3][2] = {{1, 3}, {0, 5}, {2, 4}};
    const float* xs[3] = {x_audio, x_text, x_video};

    // ---------------- Weight pre-pass ---------------------------------------
    convT(stream, proj_w,  projT, 576, 512, 3);
    convT(stream, t_qkv_w, qkvT,  512, 1536, 6);
    convT(stream, t_out_w, outT,  512, 512, 6);
    convT(stream, t_ff1_w, ff1T,  512, 2048, 6);
    convT(stream, t_ff2_w, ff2T,  2048, 512, 6);
    convT(stream, g_k_w,   gkT,   512, 512, 6);
    convT(stream, g_q_w,   gqT,   512, 512, 6);
    convT(stream, g_v_w,   gvT,   512, 512, 6);
    convT(stream, g_a_w,   gaT,   512, 512, 6);
    convT(stream, g_arel,  arelT, 64, 64, 96);
    convT(stream, g_mrel,  mrelT, 64, 64, 96);
    convT(stream, c1_w,    c1T,   1536, 768, 1);

    // ---------------- Stage 1+2: projection + transformer encoder ----------
    for (int t = 0; t < 3; ++t) {
        bf16* h = cur0 + (long)t * NH;
        xcat_k<<<(N * 576) / 256, 256, 0, stream>>>(xs[t], spk_emb, speaker_idx, xin, N * 576);
        mgemm(stream, xin, projT + (long)t * 512 * 576, proj_b + (long)t * 512, h,
              N, 576, 512, 576, 576, 512, 0, 0, 0, 1, 0);
        for (int l = 0; l < 2; ++l) {
            long wi = (long)t * 2 + l;
            mgemm(stream, h, qkvT + wi * 1536 * 512, t_qkv_b + wi * 1536, qkvb,
                  N, 512, 1536, 512, 512, 1536, 0, 0, 0, 1, 0);
            attn_k<<<dim3(D_DLG, N_HEADS), 128, 0, stream>>>(qkvb, attno);
            mgemm(stream, attno, outT + wi * 512 * 512, t_out_b + wi * 512, outp,
                  N, 512, 512, 512, 512, 512, 0, 0, 0, 1, 0);
            add_ln_k<<<N, 256, 0, stream>>>(h, outp, t_ln1_g + wi * 512, t_ln1_b + wi * 512);
            mgemm(stream, h, ff1T + wi * 2048 * 512, t_ff1_b + wi * 2048, ffb,
                  N, 512, 2048, 512, 512, 2048, 0, 0, 0, 1, 1);
            mgemm(stream, ffb, ff2T + wi * 512 * 2048, t_ff2_b + wi * 512, aux,
                  N, 2048, 512, 2048, 2048, 512, 0, 0, 0, 1, 0);
            add_ln_k<<<N, 256, 0, stream>>>(h, aux, t_ln2_g + wi * 512, t_ln2_b + wi * 512);
        }
    }

    // ---------------- Stage 3: HGT layers ----------------------------------
    bf16* cur = cur0;
    for (int l = 0; l < 2; ++l) {
        bf16* Kr  = (l == 0) ? Kbuf : cur0;
        bf16* QVr = QVbuf;
        bf16* nxt = Kr;
        for (int t = 0; t < 3; ++t) {
            long wi = (long)l * 3 + t;
            mgemm(stream, cur + (long)t * NH, gkT + wi * 512 * 512, g_k_b + wi * 512,
                  Kr + (long)t * NH, N, 512, 512, 512, 512, 512, 0, 0, 0, 1, 0);
            mgemm(stream, cur + (long)t * NH, gqT + wi * 512 * 512, g_q_b + wi * 512,
                  QVr + (long)t * NH, N, 512, 512, 512, 512, 512, 0, 0, 0, 1, 0);
        }
        // per relation: k-tilde (z=8 head-batched) + edge logits
        for (int r = 0; r < 6; ++r) {
            int st = META_S[r], dt = META_D[r];
            const bf16* arel = arelT + ((long)l * 6 + r) * 8 * 64 * 64;
            mgemm(stream, Kr + (long)st * NH, arel, nullptr, aux,
                  N, 64, 64, 512, 64, 512, 64, 64 * 64, 64, 8, 0);
            const int* srcp = edge_index + ((long)r * 2 + 0) * E_EDGES;
            const int* dstp = edge_index + ((long)r * 2 + 1) * E_EDGES;
            edge_logit_k<<<(E_EDGES * 8) / 256, 256, 0, stream>>>(
                lgbuf + (long)r * E_EDGES * 8, QVr + (long)dt * NH, aux,
                srcp, dstp, g_prel + ((long)l * 6 + r) * 8, E_EDGES);
        }
        // V projections (overwrite Q region)
        for (int t = 0; t < 3; ++t) {
            long wi = (long)l * 3 + t;
            mgemm(stream, cur + (long)t * NH, gvT + wi * 512 * 512, g_v_b + wi * 512,
                  QVr + (long)t * NH, N, 512, 512, 512, 512, 512, 0, 0, 0, 1, 0);
        }
        // per destination type
        for (int t = 0; t < 3; ++t) {
            int r0 = GROUPS[t][0], r1 = GROUPS[t][1];
            init_stats_k<<<(N * 8) / 256, 256, 0, stream>>>(mbuf, sbuf, N * 8);
            dim3 ge((E_EDGES * 8) / 256, 2);
            edge_max2_k<<<ge, 256, 0, stream>>>(lgbuf, edge_index, mbuf, r0, r1);
            edge_exp2_k<<<ge, 256, 0, stream>>>(lgbuf, edge_index, mbuf, sbuf, r0, r1);
            edge_alpha2_k<<<ge, 256, 0, stream>>>(lgbuf, edge_index, sbuf, r0, r1);
            zero_k<<<(int)(NH / 256), 256, 0, stream>>>(agg, NH);
            // m-tilde for both relations into aux / aux2
            mgemm(stream, QVr + (long)META_S[r0] * NH,
                  mrelT + ((long)l * 6 + r0) * 8 * 64 * 64, nullptr, aux,
                  N, 64, 64, 512, 64, 512, 64, 64 * 64, 64, 8, 0);
            mgemm(stream, QVr + (long)META_S[r1] * NH,
                  mrelT + ((long)l * 6 + r1) * 8 * 64 * 64, nullptr, aux2,
                  N, 64, 64, 512, 64, 512, 64, 64 * 64, 64, 8, 0);
            dim3 gs((E_EDGES * 512) / 256, 2);
            edge_scatter2_k<<<gs, 256, 0, stream>>>(lgbuf, edge_index, aux, aux2, agg, r0, r1);
            gelu_k<<<(int)(NH / 256), 256, 0, stream>>>(agg, aout, NH);
            long wi = (long)l * 3 + t;
            mgemm_f(stream, aout, gaT + wi * 512 * 512, g_a_b + wi * 512, agg,
                    N, 512, 512, 512, 512, 512, 0);
            skip_ln_relu_k<<<N, 256, 0, stream>>>(agg, cur + (long)t * NH, nxt + (long)t * NH,
                                                  g_skip + (long)l * 3 + t,
                                                  g_ln_g + wi * 512, g_ln_b + wi * 512);
        }
        cur = nxt;
    }

    // ---------------- Classifier (cur == cur0) ------------------------------
    bf16* ci = S;
    bf16* c1out = QVbuf;
    concat3_k<<<(N * 1536) / 256, 256, 0, stream>>>(cur, cur + NH, cur + 2 * NH, ci, N * 1536);
    mgemm(stream, ci, c1T, c1_b, c1out, N, 1536, 768, 1536, 1536, 768, 0, 0, 0, 1, 1);
    head7_k<<<N / 4, 256, 0, stream>>>(c1out, c2_w, c2_b, (float*)d_out);
}

// Round 7
// 3479.763 us; speedup vs baseline: 1.2105x; 1.2105x over previous
//
#include <hip/hip_runtime.h>
#include <hip/hip_bf16.h>
#include <math.h>

#define N_NODES 8192
#define D_DLG   64
#define L_SEQ   128
#define H_DIM   512
#define N_HEADS 8
#define DHEAD   64
#define FF_DIM  2048
#define E_EDGES 32768

typedef __hip_bfloat16 bf16;
typedef __attribute__((ext_vector_type(8))) short short8;
typedef __attribute__((ext_vector_type(4))) float f32x4;

// ---------------- load/store helpers (bf16 <-> f32) -------------------------
__device__ __forceinline__ float bconv(unsigned short u) {
    return __uint_as_float((unsigned)u << 16);
}
__device__ __forceinline__ unsigned short fconv(float f) {
    bf16 h = __float2bfloat16(f);
    return *(unsigned short*)&h;
}
__device__ __forceinline__ float4 ld4(const float* p) { return *(const float4*)p; }
__device__ __forceinline__ float4 ld4(const bf16* p) {
    ushort4 u = *(const ushort4*)p;
    float4 v;
    v.x = bconv(u.x); v.y = bconv(u.y); v.z = bconv(u.z); v.w = bconv(u.w);
    return v;
}
__device__ __forceinline__ float ld1(const float* p) { return *p; }
__device__ __forceinline__ float ld1(const bf16* p) { return bconv(*(const unsigned short*)p); }
__device__ __forceinline__ void st1(float* p, float v) { *p = v; }
__device__ __forceinline__ void st1(bf16* p, float v) { *p = __float2bfloat16(v); }

__device__ __forceinline__ void gld_lds16(const bf16* g, bf16* l) {
    __builtin_amdgcn_global_load_lds(
        (const __attribute__((address_space(1))) void*)g,
        (__attribute__((address_space(3))) void*)l, 16, 0, 0);
}

// ---------------------------------------------------------------------------
// Weight pre-pass: f32 [z][K][N] -> bf16 [z][N][K] (transpose + convert).
// ---------------------------------------------------------------------------
__global__ __launch_bounds__(256) void transpose_k(const float* __restrict__ in,
                                                   bf16* __restrict__ out, int K, int N)
{
    __shared__ float tile[32][33];
    const long zoff = (long)blockIdx.z * K * N;
    const int n0 = blockIdx.x * 32, k0 = blockIdx.y * 32;
    const int tx = threadIdx.x, ty = threadIdx.y;
#pragma unroll
    for (int i = 0; i < 4; ++i)
        tile[ty + i * 8][tx] = in[zoff + (long)(k0 + ty + i * 8) * N + n0 + tx];
    __syncthreads();
#pragma unroll
    for (int i = 0; i < 4; ++i)
        st1(out + zoff + (long)(n0 + ty + i * 8) * K + k0 + tx, tile[tx][ty + i * 8]);
}

// ---------------------------------------------------------------------------
// MFMA GEMM: C = act(A @ Bt^T + bias). A bf16 [M][K] (lda), Bt bf16 [N][K]
// (ldb), C row-major (ldc). 128x128 tile, BK=32, 4 waves, 4x4 mfma/wave.
// ---------------------------------------------------------------------------
template <typename TC>
__global__ __launch_bounds__(256) void mgemm_k(
    const bf16* __restrict__ A, const bf16* __restrict__ Bt,
    const float* __restrict__ bias, TC* __restrict__ C,
    int M, int K, int Ncols, int lda, int ldb, int ldc,
    long sA, long sB, long sC, int act)
{
    A  += (long)blockIdx.z * sA;
    Bt += (long)blockIdx.z * sB;
    C  += (long)blockIdx.z * sC;

    __shared__ bf16 As[128 * 32];
    __shared__ bf16 Bs[128 * 32];

    const int tid  = threadIdx.x;
    const int lane = tid & 63;
    const int wave = tid >> 6;
    const int wr   = wave >> 1;
    const int wc   = wave & 1;
    const int rowTile = blockIdx.y * 128;
    const int colTile = blockIdx.x * 128;

    const int c0 = wave * 2, c1 = wave * 2 + 1;
    const int b0 = c0 * 1024 + lane * 16;
    const int b1 = c1 * 1024 + lane * 16;
    const int ar0 = b0 >> 6, ak0 = (b0 & 63) >> 1;
    const int ar1 = b1 >> 6, ak1 = (b1 & 63) >> 1;

    const int frow = lane & 15;
    const int kgrp = lane >> 4;

    f32x4 acc[4][4];
#pragma unroll
    for (int i = 0; i < 4; ++i)
#pragma unroll
        for (int j = 0; j < 4; ++j) acc[i][j] = (f32x4){0.f, 0.f, 0.f, 0.f};

    for (int k0 = 0; k0 < K; k0 += 32) {
        gld_lds16(A  + (long)(rowTile + ar0) * lda + k0 + ak0, As + c0 * 512);
        gld_lds16(A  + (long)(rowTile + ar1) * lda + k0 + ak1, As + c1 * 512);
        gld_lds16(Bt + (long)(colTile + ar0) * ldb + k0 + ak0, Bs + c0 * 512);
        gld_lds16(Bt + (long)(colTile + ar1) * ldb + k0 + ak1, Bs + c1 * 512);
        __syncthreads();

        short8 av[4], bv[4];
#pragma unroll
        for (int mi = 0; mi < 4; ++mi)
            av[mi] = *(const short8*)(As + (wr * 64 + mi * 16 + frow) * 32 + kgrp * 8);
#pragma unroll
        for (int ni = 0; ni < 4; ++ni)
            bv[ni] = *(const short8*)(Bs + (wc * 64 + ni * 16 + frow) * 32 + kgrp * 8);
#pragma unroll
        for (int mi = 0; mi < 4; ++mi)
#pragma unroll
            for (int ni = 0; ni < 4; ++ni)
                acc[mi][ni] = __builtin_amdgcn_mfma_f32_16x16x32_bf16(
                    av[mi], bv[ni], acc[mi][ni], 0, 0, 0);
        __syncthreads();
    }

#pragma unroll
    for (int ni = 0; ni < 4; ++ni) {
        int col = colTile + wc * 64 + ni * 16 + frow;
        if (col < Ncols) {
            float bb = bias ? bias[col] : 0.f;
#pragma unroll
            for (int mi = 0; mi < 4; ++mi) {
                long rbase = rowTile + wr * 64 + mi * 16 + kgrp * 4;
#pragma unroll
                for (int r = 0; r < 4; ++r) {
                    float v = acc[mi][ni][r] + bb;
                    if (act == 1) v = fmaxf(v, 0.f);
                    st1(C + (rbase + r) * (long)ldc + col, v);
                }
            }
        }
    }
}

// ---------------------------------------------------------------------------
// MFMA flash attention per (dialogue, head). 256 thr = 4 waves.
// S=QK^T (waves 2x2, frags direct global->reg), in-register softmax with
// 2KB LDS cross-wave merge, P->LDS (A-layout), O=P@V (V transposed in LDS).
// ---------------------------------------------------------------------------
__global__ __launch_bounds__(256) void attn_mfma_k(const bf16* __restrict__ qkv,
                                                   bf16* __restrict__ o)
{
    __shared__ bf16 Pb[128 * 136];   // 34.8 KB, A-layout P
    __shared__ bf16 Vt[64 * 136];    // 17.4 KB, V^T [dh][l]
    __shared__ float pm[128][2];     // per-row partial max (per wave-col)
    __shared__ float ps[128][2];     // per-row partial sum

    const int d = blockIdx.x, h = blockIdx.y;
    const long base = (long)d * L_SEQ;
    const int tid  = threadIdx.x;
    const int lane = tid & 63;
    const int wave = tid >> 6;
    const int frow = lane & 15;
    const int kgrp = lane >> 4;
    const int wr = wave >> 1;        // S row-half
    const int wc = wave & 1;         // S col-half
    const float SC = 0.125f;

    // ---- V[l][dh] -> Vt[dh][l] (one-time scalar transpose) -----------------
    {
        int l = tid >> 1, dh0 = (tid & 1) * 32;
        const bf16* vp = qkv + (base + l) * 1536 + 1024 + h * 64 + dh0;
        unsigned short* vt = (unsigned short*)Vt;
#pragma unroll
        for (int j = 0; j < 4; ++j) {
            short8 v = *(const short8*)(vp + j * 8);
#pragma unroll
            for (int jj = 0; jj < 8; ++jj)
                vt[(dh0 + j * 8 + jj) * 136 + l] = (unsigned short)v[jj];
        }
    }

    // ---- Q,K fragments direct from global (no reuse -> no LDS) -------------
    short8 aq[4][2], bk[4][2];
#pragma unroll
    for (int mi = 0; mi < 4; ++mi) {
        long row = base + wr * 64 + mi * 16 + frow;
#pragma unroll
        for (int ks = 0; ks < 2; ++ks)
            aq[mi][ks] = *(const short8*)(qkv + row * 1536 + h * 64 + ks * 32 + kgrp * 8);
    }
#pragma unroll
    for (int ni = 0; ni < 4; ++ni) {
        long row = base + wc * 64 + ni * 16 + frow;
#pragma unroll
        for (int ks = 0; ks < 2; ++ks)
            bk[ni][ks] = *(const short8*)(qkv + row * 1536 + 512 + h * 64 + ks * 32 + kgrp * 8);
    }

    // ---- S = Q @ K^T (64x64 per wave) --------------------------------------
    f32x4 acc[4][4];
#pragma unroll
    for (int i = 0; i < 4; ++i)
#pragma unroll
        for (int j = 0; j < 4; ++j) acc[i][j] = (f32x4){0.f, 0.f, 0.f, 0.f};
#pragma unroll
    for (int ks = 0; ks < 2; ++ks)
#pragma unroll
        for (int mi = 0; mi < 4; ++mi)
#pragma unroll
            for (int ni = 0; ni < 4; ++ni)
                acc[mi][ni] = __builtin_amdgcn_mfma_f32_16x16x32_bf16(
                    aq[mi][ks], bk[ni][ks], acc[mi][ni], 0, 0, 0);

    // ---- per-wave row partials (rows = wr*64 + mi*16 + kgrp*4 + r) ---------
#pragma unroll
    for (int mi = 0; mi < 4; ++mi) {
#pragma unroll
        for (int r = 0; r < 4; ++r) {
            float mv = -1e30f;
#pragma unroll
            for (int ni = 0; ni < 4; ++ni) mv = fmaxf(mv, acc[mi][ni][r] * SC);
#pragma unroll
            for (int off = 1; off < 16; off <<= 1)
                mv = fmaxf(mv, __shfl_xor(mv, off, 64));
            float sv = 0.f;
#pragma unroll
            for (int ni = 0; ni < 4; ++ni) sv += __expf(acc[mi][ni][r] * SC - mv);
#pragma unroll
            for (int off = 1; off < 16; off <<= 1)
                sv += __shfl_xor(sv, off, 64);
            if (frow == 0) {
                int row = wr * 64 + mi * 16 + kgrp * 4 + r;
                pm[row][wc] = mv;
                ps[row][wc] = sv;
            }
        }
    }
    __syncthreads();

    // ---- merge halves, write P (bf16, A-layout) ----------------------------
    unsigned short* pb = (unsigned short*)Pb;
#pragma unroll
    for (int mi = 0; mi < 4; ++mi) {
#pragma unroll
        for (int r = 0; r < 4; ++r) {
            int row = wr * 64 + mi * 16 + kgrp * 4 + r;
            float m0 = pm[row][0], m1 = pm[row][1];
            float M = fmaxf(m0, m1);
            float Ssum = ps[row][0] * __expf(m0 - M) + ps[row][1] * __expf(m1 - M);
            float inv = 1.f / Ssum;
#pragma unroll
            for (int ni = 0; ni < 4; ++ni) {
                int col = wc * 64 + ni * 16 + frow;
                float p = __expf(acc[mi][ni][r] * SC - M) * inv;
                pb[row * 136 + col] = fconv(p);
            }
        }
    }
    __syncthreads();

    // ---- O = P @ V (wave handles 32 rows; N = 64 = DHEAD) ------------------
    f32x4 acc2[2][4];
#pragma unroll
    for (int i = 0; i < 2; ++i)
#pragma unroll
        for (int j = 0; j < 4; ++j) acc2[i][j] = (f32x4){0.f, 0.f, 0.f, 0.f};
#pragma unroll
    for (int ks = 0; ks < 4; ++ks) {
        short8 ap[2], bv[4];
#pragma unroll
        for (int mi = 0; mi < 2; ++mi)
            ap[mi] = *(const short8*)(Pb + (wave * 32 + mi * 16 + frow) * 136 + ks * 32 + kgrp * 8);
#pragma unroll
        for (int ni = 0; ni < 4; ++ni)
            bv[ni] = *(const short8*)(Vt + (ni * 16 + frow) * 136 + ks * 32 + kgrp * 8);
#pragma unroll
        for (int mi = 0; mi < 2; ++mi)
#pragma unroll
            for (int ni = 0; ni < 4; ++ni)
                acc2[mi][ni] = __builtin_amdgcn_mfma_f32_16x16x32_bf16(
                    ap[mi], bv[ni], acc2[mi][ni], 0, 0, 0);
    }
#pragma unroll
    for (int mi = 0; mi < 2; ++mi) {
#pragma unroll
        for (int ni = 0; ni < 4; ++ni) {
            int col = ni * 16 + frow;
            long rowb = wave * 32 + mi * 16 + kgrp * 4;
#pragma unroll
            for (int r = 0; r < 4; ++r)
                st1(o + (base + rowb + r) * 512 + h * 64 + col, acc2[mi][ni][r]);
        }
    }
}

// ---------------------------------------------------------------------------
// Classifier head: out[N,7] = A[N,768] @ W[768,7] + bias. Wave per row.
// ---------------------------------------------------------------------------
__global__ __launch_bounds__(256) void head7_k(
    const bf16* __restrict__ A, const float* __restrict__ W,
    const float* __restrict__ bias, float* __restrict__ out)
{
    const int wave = threadIdx.x >> 6, lane = threadIdx.x & 63;
    const long row = blockIdx.x * 4 + wave;
    const bf16* a = A + row * 768;
    float acc[7];
#pragma unroll
    for (int j = 0; j < 7; ++j) acc[j] = 0.f;
#pragma unroll
    for (int i = 0; i < 12; ++i) {
        int k = lane + i * 64;
        float av = ld1(a + k);
        const float* w = W + k * 7;
#pragma unroll
        for (int j = 0; j < 7; ++j) acc[j] = fmaf(av, w[j], acc[j]);
    }
#pragma unroll
    for (int j = 0; j < 7; ++j)
#pragma unroll
        for (int o = 32; o > 0; o >>= 1) acc[j] += __shfl_down(acc[j], o, 64);
    if (lane == 0) {
#pragma unroll
        for (int j = 0; j < 7; ++j) out[row * 7 + j] = acc[j] + bias[j];
    }
}

// ---------------------------------------------------------------------------
__global__ void xcat_k(const float* __restrict__ x, const float* __restrict__ spk_emb,
                       const int* __restrict__ sidx, bf16* __restrict__ out, int n_total)
{
    int i = blockIdx.x * 256 + threadIdx.x;
    if (i >= n_total) return;
    int n = i / 576;
    int c = i - n * 576;
    st1(out + i, (c < 512) ? x[(long)n * 512 + c]
                           : spk_emb[(long)sidx[n] * 64 + (c - 512)]);
}

// ---------------------------------------------------------------------------
__global__ __launch_bounds__(256) void add_ln_k(bf16* __restrict__ h, const bf16* __restrict__ r,
                                                const float* __restrict__ g, const float* __restrict__ b)
{
    const int row = blockIdx.x;
    const int tid = threadIdx.x;
    const long base = (long)row * 512;
    float x0 = ld1(h + base + tid) + ld1(r + base + tid);
    float x1 = ld1(h + base + tid + 256) + ld1(r + base + tid + 256);
    float s = x0 + x1;
    float q = x0 * x0 + x1 * x1;
#pragma unroll
    for (int o = 32; o > 0; o >>= 1) { s += __shfl_down(s, o, 64); q += __shfl_down(q, o, 64); }
    __shared__ float ls[4], lq[4];
    if ((tid & 63) == 0) { ls[tid >> 6] = s; lq[tid >> 6] = q; }
    __syncthreads();
    float S = ls[0] + ls[1] + ls[2] + ls[3];
    float Q = lq[0] + lq[1] + lq[2] + lq[3];
    float mu = S * (1.f / 512.f);
    float var = Q * (1.f / 512.f) - mu * mu;
    float inv = rsqrtf(fmaxf(var, 0.f) + 1e-5f);
    st1(h + base + tid,       (x0 - mu) * inv * g[tid] + b[tid]);
    st1(h + base + tid + 256, (x1 - mu) * inv * g[tid + 256] + b[tid + 256]);
}

__global__ __launch_bounds__(256) void skip_ln_relu_k(
    const float* __restrict__ outp, const bf16* __restrict__ curp, bf16* __restrict__ dst,
    const float* __restrict__ gskip, const float* __restrict__ g, const float* __restrict__ b)
{
    const int row = blockIdx.x;
    const int tid = threadIdx.x;
    const float beta = 1.f / (1.f + __expf(-gskip[0]));
    const long base = (long)row * 512;
    float x0 = beta * outp[base + tid]       + (1.f - beta) * ld1(curp + base + tid);
    float x1 = beta * outp[base + tid + 256] + (1.f - beta) * ld1(curp + base + tid + 256);
    float s = x0 + x1;
    float q = x0 * x0 + x1 * x1;
#pragma unroll
    for (int o = 32; o > 0; o >>= 1) { s += __shfl_down(s, o, 64); q += __shfl_down(q, o, 64); }
    __shared__ float ls[4], lq[4];
    if ((tid & 63) == 0) { ls[tid >> 6] = s; lq[tid >> 6] = q; }
    __syncthreads();
    float S = ls[0] + ls[1] + ls[2] + ls[3];
    float Q = lq[0] + lq[1] + lq[2] + lq[3];
    float mu = S * (1.f / 512.f);
    float var = Q * (1.f / 512.f) - mu * mu;
    float inv = rsqrtf(fmaxf(var, 0.f) + 1e-5f);
    float y0 = (x0 - mu) * inv * g[tid] + b[tid];
    float y1 = (x1 - mu) * inv * g[tid + 256] + b[tid + 256];
    st1(dst + base + tid,       fmaxf(y0, 0.f));
    st1(dst + base + tid + 256, fmaxf(y1, 0.f));
}

// ---------------------------------------------------------------------------
__device__ __forceinline__ unsigned enc_f(float f) {
    unsigned u = __float_as_uint(f);
    return (u & 0x80000000u) ? ~u : (u | 0x80000000u);
}
__device__ __forceinline__ float dec_f(unsigned u) {
    return (u & 0x80000000u) ? __uint_as_float(u & 0x7fffffffu) : __uint_as_float(~u);
}

__global__ void edge_logit_k(float* __restrict__ lg, const bf16* __restrict__ qq,
                             const bf16* __restrict__ ktmp, const int* __restrict__ src,
                             const int* __restrict__ dst, const float* __restrict__ prel, int E)
{
    int tid = blockIdx.x * 256 + threadIdx.x;
    int e = tid >> 3;
    int h = tid & 7;
    if (e >= E) return;
    const bf16* qp = qq   + (long)dst[e] * 512 + h * 64;
    const bf16* kp = ktmp + (long)src[e] * 512 + h * 64;
    float acc = 0.f;
#pragma unroll
    for (int i = 0; i < 64; i += 4) {
        float4 a = ld4(qp + i);
        float4 c = ld4(kp + i);
        acc = fmaf(a.x, c.x, acc); acc = fmaf(a.y, c.y, acc);
        acc = fmaf(a.z, c.z, acc); acc = fmaf(a.w, c.w, acc);
    }
    lg[(long)e * 8 + h] = acc * prel[h] * 0.125f;
}

__global__ void init_stats_k(unsigned* __restrict__ m, float* __restrict__ s, int n)
{
    int i = blockIdx.x * 256 + threadIdx.x;
    if (i < n) { m[i] = 0x007FFFFFu; s[i] = 0.f; }
}

__global__ void edge_max2_k(const float* __restrict__ lgbuf, const int* __restrict__ ei,
                            unsigned* __restrict__ m, int r0, int r1)
{
    int r = blockIdx.y ? r1 : r0;
    const float* lg = lgbuf + (long)r * E_EDGES * 8;
    const int* dst = ei + ((long)r * 2 + 1) * E_EDGES;
    int tid = blockIdx.x * 256 + threadIdx.x;
    int e = tid >> 3;
    int h = tid & 7;
    if (e >= E_EDGES) return;
    atomicMax(&m[(long)dst[e] * 8 + h], enc_f(lg[(long)e * 8 + h]));
}

__global__ void edge_exp2_k(float* __restrict__ lgbuf, const int* __restrict__ ei,
                            const unsigned* __restrict__ m, float* __restrict__ s,
                            int r0, int r1)
{
    int r = blockIdx.y ? r1 : r0;
    float* lg = lgbuf + (long)r * E_EDGES * 8;
    const int* dst = ei + ((long)r * 2 + 1) * E_EDGES;
    int tid = blockIdx.x * 256 + threadIdx.x;
    int e = tid >> 3;
    int h = tid & 7;
    if (e >= E_EDGES) return;
    long si = (long)dst[e] * 8 + h;
    float mv = dec_f(m[si]);
    float ev = __expf(lg[(long)e * 8 + h] - mv);
    lg[(long)e * 8 + h] = ev;
    atomicAdd(&s[si], ev);
}

__global__ void edge_alpha2_k(float* __restrict__ lgbuf, const int* __restrict__ ei,
                              const float* __restrict__ s, int r0, int r1)
{
    int r = blockIdx.y ? r1 : r0;
    float* lg = lgbuf + (long)r * E_EDGES * 8;
    const int* dst = ei + ((long)r * 2 + 1) * E_EDGES;
    int tid = blockIdx.x * 256 + threadIdx.x;
    int e = tid >> 3;
    int h = tid & 7;
    if (e >= E_EDGES) return;
    lg[(long)e * 8 + h] = lg[(long)e * 8 + h] / (s[(long)dst[e] * 8 + h] + 1e-9f);
}

__global__ void edge_scatter2_k(const float* __restrict__ lgbuf, const int* __restrict__ ei,
                                const bf16* __restrict__ vt0, const bf16* __restrict__ vt1,
                                float* __restrict__ agg, int r0, int r1)
{
    int gi = blockIdx.y;
    int r = gi ? r1 : r0;
    const float* lg = lgbuf + (long)r * E_EDGES * 8;
    const int* src = ei + ((long)r * 2 + 0) * E_EDGES;
    const int* dst = ei + ((long)r * 2 + 1) * E_EDGES;
    const bf16* vtmp = gi ? vt1 : vt0;
    int tid = blockIdx.x * 256 + threadIdx.x;
    int e = tid >> 9;
    int c = tid & 511;
    int h = c >> 6;
    if (e >= E_EDGES) return;
    int de = dst[e];
    float a = lg[(long)e * 8 + h];
    atomicAdd(&agg[(long)de * 512 + c], a * ld1(vtmp + (long)src[e] * 512 + c));
}

__global__ void zero_k(float* __restrict__ p, long n)
{
    long i = (long)blockIdx.x * 256 + threadIdx.x;
    if (i < n) p[i] = 0.f;
}

__global__ void gelu_k(const float* __restrict__ x, bf16* __restrict__ y, long n)
{
    long i = (long)blockIdx.x * 256 + threadIdx.x;
    if (i < n) {
        float v = x[i];
        float t = tanhf(0.79788456080286535588f * (v + 0.044715f * v * v * v));
        st1(y + i, 0.5f * v * (1.f + t));
    }
}

__global__ void concat3_k(const bf16* __restrict__ a, const bf16* __restrict__ b,
                          const bf16* __restrict__ c, bf16* __restrict__ out, int n_total)
{
    int i = blockIdx.x * 256 + threadIdx.x;
    if (i >= n_total) return;
    int n = i / 1536;
    int cc = i - n * 1536;
    const bf16* sp = (cc < 512) ? a : (cc < 1024 ? b : c);
    out[i] = sp[(long)n * 512 + (cc & 511)];
}

// ---------------------------------------------------------------------------
static inline void convT(hipStream_t st, const float* in, bf16* out, int K, int N, int z)
{
    dim3 g(N / 32, K / 32, z), b(32, 8);
    transpose_k<<<g, b, 0, st>>>(in, out, K, N);
}
static inline void mgemm(hipStream_t st, const bf16* A, const bf16* Bt, const float* bias,
                         bf16* C, int M, int K, int Ncols, int lda, int ldb, int ldc,
                         long sA, long sB, long sC, int z, int act)
{
    dim3 g((Ncols + 127) / 128, M / 128, z);
    mgemm_k<bf16><<<g, 256, 0, st>>>(A, Bt, bias, C, M, K, Ncols, lda, ldb, ldc, sA, sB, sC, act);
}
static inline void mgemm_f(hipStream_t st, const bf16* A, const bf16* Bt, const float* bias,
                           float* C, int M, int K, int Ncols, int lda, int ldb, int ldc, int act)
{
    dim3 g((Ncols + 127) / 128, M / 128, 1);
    mgemm_k<float><<<g, 256, 0, st>>>(A, Bt, bias, C, M, K, Ncols, lda, ldb, ldc, 0, 0, 0, act);
}

extern "C" void kernel_launch(void* const* d_in, const int* in_sizes, int n_in,
                              void* d_out, int out_size, void* d_ws, size_t ws_size,
                              hipStream_t stream)
{
    const float* x_audio = (const float*)d_in[0];
    const float* x_text  = (const float*)d_in[1];
    const float* x_video = (const float*)d_in[2];
    const float* spk_emb = (const float*)d_in[3];
    const float* proj_w  = (const float*)d_in[4];
    const float* proj_b  = (const float*)d_in[5];
    const float* t_qkv_w = (const float*)d_in[6];
    const float* t_qkv_b = (const float*)d_in[7];
    const float* t_out_w = (const float*)d_in[8];
    const float* t_out_b = (const float*)d_in[9];
    const float* t_ff1_w = (const float*)d_in[10];
    const float* t_ff1_b = (const float*)d_in[11];
    const float* t_ff2_w = (const float*)d_in[12];
    const float* t_ff2_b = (const float*)d_in[13];
    const float* t_ln1_g = (const float*)d_in[14];
    const float* t_ln1_b = (const float*)d_in[15];
    const float* t_ln2_g = (const float*)d_in[16];
    const float* t_ln2_b = (const float*)d_in[17];
    const float* g_k_w   = (const float*)d_in[18];
    const float* g_k_b   = (const float*)d_in[19];
    const float* g_q_w   = (const float*)d_in[20];
    const float* g_q_b   = (const float*)d_in[21];
    const float* g_v_w   = (const float*)d_in[22];
    const float* g_v_b   = (const float*)d_in[23];
    const float* g_a_w   = (const float*)d_in[24];
    const float* g_a_b   = (const float*)d_in[25];
    const float* g_skip  = (const float*)d_in[26];
    const float* g_arel  = (const float*)d_in[27];
    const float* g_mrel  = (const float*)d_in[28];
    const float* g_prel  = (const float*)d_in[29];
    const float* g_ln_g  = (const float*)d_in[30];
    const float* g_ln_b  = (const float*)d_in[31];
    const float* c1_w    = (const float*)d_in[32];
    const float* c1_b    = (const float*)d_in[33];
    const float* c2_w    = (const float*)d_in[34];
    const float* c2_b    = (const float*)d_in[35];
    const int* speaker_idx = (const int*)d_in[36];
    const int* edge_index  = (const int*)d_in[38];

    const int N = N_NODES;
    const long NH = (long)N_NODES * H_DIM;

    // ---- bf16-transposed weight region (~56 MB) ----------------------------
    bf16* Wbf = (bf16*)d_ws;
    long off = 0;
    bf16* projT = Wbf + off; off += 3L * 512 * 576;
    bf16* qkvT  = Wbf + off; off += 6L * 1536 * 512;
    bf16* outT  = Wbf + off; off += 6L * 512 * 512;
    bf16* ff1T  = Wbf + off; off += 6L * 2048 * 512;
    bf16* ff2T  = Wbf + off; off += 6L * 512 * 2048;
    bf16* gkT   = Wbf + off; off += 6L * 512 * 512;
    bf16* gqT   = Wbf + off; off += 6L * 512 * 512;
    bf16* gvT   = Wbf + off; off += 6L * 512 * 512;
    bf16* gaT   = Wbf + off; off += 6L * 512 * 512;
    bf16* arelT = Wbf + off; off += 96L * 64 * 64;
    bf16* mrelT = Wbf + off; off += 96L * 64 * 64;
    bf16* c1T   = Wbf + off; off += 768L * 1536;
    off += 4096;  // slack for N=64 tile over-reads

    // ---- activation workspace (~126 MB; total ~183 MB) ---------------------
    bf16* cur0  = Wbf + off;
    bf16* Kbuf  = cur0 + 3 * NH;
    bf16* QVbuf = Kbuf + 3 * NH;
    bf16* S     = QVbuf + 3 * NH;          // N*2048 scratch
    bf16* aux   = S + (long)N * 2048;      // 2*NH
    bf16* aux2  = aux + NH;

    bf16* xin   = S;
    bf16* qkvb  = S;
    bf16* attno = S + (long)N * 1536;
    bf16* outp  = S;
    bf16* ffb   = S;
    float* agg   = (float*)S;
    float* lgbuf = agg + NH;
    unsigned* mbuf = (unsigned*)(lgbuf + 6L * E_EDGES * 8);
    float* sbuf  = (float*)(mbuf + (long)N * 8);
    bf16* aout   = (bf16*)(sbuf + (long)N * 8);

    static const int META_S[6] = {0, 1, 0, 2, 1, 2};
    static const int META_D[6] = {1, 0, 2, 0, 2, 1};
    static const int GROUPS[3][2] = {{1, 3}, {0, 5}, {2, 4}};
    const float* xs[3] = {x_audio, x_text, x_video};

    // ---------------- Weight pre-pass ---------------------------------------
    convT(stream, proj_w,  projT, 576, 512, 3);
    convT(stream, t_qkv_w, qkvT,  512, 1536, 6);
    convT(stream, t_out_w, outT,  512, 512, 6);
    convT(stream, t_ff1_w, ff1T,  512, 2048, 6);
    convT(stream, t_ff2_w, ff2T,  2048, 512, 6);
    convT(stream, g_k_w,   gkT,   512, 512, 6);
    convT(stream, g_q_w,   gqT,   512, 512, 6);
    convT(stream, g_v_w,   gvT,   512, 512, 6);
    convT(stream, g_a_w,   gaT,   512, 512, 6);
    convT(stream, g_arel,  arelT, 64, 64, 96);
    convT(stream, g_mrel,  mrelT, 64, 64, 96);
    convT(stream, c1_w,    c1T,   1536, 768, 1);

    // ---------------- Stage 1+2: projection + transformer encoder ----------
    for (int t = 0; t < 3; ++t) {
        bf16* h = cur0 + (long)t * NH;
        xcat_k<<<(N * 576) / 256, 256, 0, stream>>>(xs[t], spk_emb, speaker_idx, xin, N * 576);
        mgemm(stream, xin, projT + (long)t * 512 * 576, proj_b + (long)t * 512, h,
              N, 576, 512, 576, 576, 512, 0, 0, 0, 1, 0);
        for (int l = 0; l < 2; ++l) {
            long wi = (long)t * 2 + l;
            mgemm(stream, h, qkvT + wi * 1536 * 512, t_qkv_b + wi * 1536, qkvb,
                  N, 512, 1536, 512, 512, 1536, 0, 0, 0, 1, 0);
            attn_mfma_k<<<dim3(D_DLG, N_HEADS), 256, 0, stream>>>(qkvb, attno);
            mgemm(stream, attno, outT + wi * 512 * 512, t_out_b + wi * 512, outp,
                  N, 512, 512, 512, 512, 512, 0, 0, 0, 1, 0);
            add_ln_k<<<N, 256, 0, stream>>>(h, outp, t_ln1_g + wi * 512, t_ln1_b + wi * 512);
            mgemm(stream, h, ff1T + wi * 2048 * 512, t_ff1_b + wi * 2048, ffb,
                  N, 512, 2048, 512, 512, 2048, 0, 0, 0, 1, 1);
            mgemm(stream, ffb, ff2T + wi * 512 * 2048, t_ff2_b + wi * 512, aux,
                  N, 2048, 512, 2048, 2048, 512, 0, 0, 0, 1, 0);
            add_ln_k<<<N, 256, 0, stream>>>(h, aux, t_ln2_g + wi * 512, t_ln2_b + wi * 512);
        }
    }

    // ---------------- Stage 3: HGT layers ----------------------------------
    bf16* cur = cur0;
    for (int l = 0; l < 2; ++l) {
        bf16* Kr  = (l == 0) ? Kbuf : cur0;
        bf16* QVr = QVbuf;
        bf16* nxt = Kr;
        for (int t = 0; t < 3; ++t) {
            long wi = (long)l * 3 + t;
            mgemm(stream, cur + (long)t * NH, gkT + wi * 512 * 512, g_k_b + wi * 512,
                  Kr + (long)t * NH, N, 512, 512, 512, 512, 512, 0, 0, 0, 1, 0);
            mgemm(stream, cur + (long)t * NH, gqT + wi * 512 * 512, g_q_b + wi * 512,
                  QVr + (long)t * NH, N, 512, 512, 512, 512, 512, 0, 0, 0, 1, 0);
        }
        for (int r = 0; r < 6; ++r) {
            int st = META_S[r], dt = META_D[r];
            const bf16* arel = arelT + ((long)l * 6 + r) * 8 * 64 * 64;
            mgemm(stream, Kr + (long)st * NH, arel, nullptr, aux,
                  N, 64, 64, 512, 64, 512, 64, 64 * 64, 64, 8, 0);
            const int* srcp = edge_index + ((long)r * 2 + 0) * E_EDGES;
            const int* dstp = edge_index + ((long)r * 2 + 1) * E_EDGES;
            edge_logit_k<<<(E_EDGES * 8) / 256, 256, 0, stream>>>(
                lgbuf + (long)r * E_EDGES * 8, QVr + (long)dt * NH, aux,
                srcp, dstp, g_prel + ((long)l * 6 + r) * 8, E_EDGES);
        }
        for (int t = 0; t < 3; ++t) {
            long wi = (long)l * 3 + t;
            mgemm(stream, cur + (long)t * NH, gvT + wi * 512 * 512, g_v_b + wi * 512,
                  QVr + (long)t * NH, N, 512, 512, 512, 512, 512, 0, 0, 0, 1, 0);
        }
        for (int t = 0; t < 3; ++t) {
            int r0 = GROUPS[t][0], r1 = GROUPS[t][1];
            init_stats_k<<<(N * 8) / 256, 256, 0, stream>>>(mbuf, sbuf, N * 8);
            dim3 ge((E_EDGES * 8) / 256, 2);
            edge_max2_k<<<ge, 256, 0, stream>>>(lgbuf, edge_index, mbuf, r0, r1);
            edge_exp2_k<<<ge, 256, 0, stream>>>(lgbuf, edge_index, mbuf, sbuf, r0, r1);
            edge_alpha2_k<<<ge, 256, 0, stream>>>(lgbuf, edge_index, sbuf, r0, r1);
            zero_k<<<(int)(NH / 256), 256, 0, stream>>>(agg, NH);
            mgemm(stream, QVr + (long)META_S[r0] * NH,
                  mrelT + ((long)l * 6 + r0) * 8 * 64 * 64, nullptr, aux,
                  N, 64, 64, 512, 64, 512, 64, 64 * 64, 64, 8, 0);
            mgemm(stream, QVr + (long)META_S[r1] * NH,
                  mrelT + ((long)l * 6 + r1) * 8 * 64 * 64, nullptr, aux2,
                  N, 64, 64, 512, 64, 512, 64, 64 * 64, 64, 8, 0);
            dim3 gs((E_EDGES * 512) / 256, 2);
            edge_scatter2_k<<<gs, 256, 0, stream>>>(lgbuf, edge_index, aux, aux2, agg, r0, r1);
            gelu_k<<<(int)(NH / 256), 256, 0, stream>>>(agg, aout, NH);
            long wi = (long)l * 3 + t;
            mgemm_f(stream, aout, gaT + wi * 512 * 512, g_a_b + wi * 512, agg,
                    N, 512, 512, 512, 512, 512, 0);
            skip_ln_relu_k<<<N, 256, 0, stream>>>(agg, cur + (long)t * NH, nxt + (long)t * NH,
                                                  g_skip + (long)l * 3 + t,
                                                  g_ln_g + wi * 512, g_ln_b + wi * 512);
        }
        cur = nxt;
    }

    // ---------------- Classifier (cur == cur0) ------------------------------
    bf16* ci = S;
    bf16* c1out = QVbuf;
    concat3_k<<<(N * 1536) / 256, 256, 0, stream>>>(cur, cur + NH, cur + 2 * NH, ci, N * 1536);
    mgemm(stream, ci, c1T, c1_b, c1out, N, 1536, 768, 1536, 1536, 768, 0, 0, 0, 1, 1);
    head7_k<<<N / 4, 256, 0, stream>>>(c1out, c2_w, c2_b, (float*)d_out);
}